// Round 1
// baseline (1244.313 us; speedup 1.0000x reference)
//
#include <hip/hip_runtime.h>
#include <stdint.h>

#define NN 100000
#define NE 1000000

// ws layout (bytes)
static const size_t OFF_DENOM = 0;                    // NN f32 (400,000 B)
static const size_t OFF_MT    = 1u << 19;             // 16384 f32: MT[l][i] = (W1a@Wq)[i][l]
static const size_t OFF_W1BT  = OFF_MT + 65536;       // 16384 bf16 (ushort): w1bt[j][i] = bf16(W1[i][128+j])
static const size_t OFF_EVALS = OFF_W1BT + 32768;     // NE f32
static const size_t OFF_SNODE = OFF_EVALS + 4000000;  // NN*128 f32
// total ≈ 55.8 MB

__device__ inline float4 fma4(float a, float4 b, float4 c) {
    c.x = fmaf(a, b.x, c.x);
    c.y = fmaf(a, b.y, c.y);
    c.z = fmaf(a, b.z, c.z);
    c.w = fmaf(a, b.w, c.w);
    return c;
}

// ---------------------------------------------------------------------------
// prep: MT[l][i] = sum_j W1[i][j]*Wq[j][l]   (M = W1a@Wq, stored transposed)
//       w1bt[j][i] = bf16(W1[i][128+j])      (W1b^T in bf16 for LDS staging)
// ---------------------------------------------------------------------------
__global__ __launch_bounds__(128) void prep_kernel(
    const float* __restrict__ W1, const float* __restrict__ Wq,
    float* __restrict__ MT, unsigned short* __restrict__ w1bt)
{
    const int l = blockIdx.x;   // 0..127
    const int i = threadIdx.x;  // 0..127
    float acc = 0.f;
#pragma unroll 8
    for (int j = 0; j < 128; ++j)
        acc = fmaf(W1[i * 256 + j], Wq[j * 128 + l], acc);
    MT[l * 128 + i] = acc;
    const float w = W1[i * 256 + 128 + l];
    const unsigned int b = __float_as_uint(w);
    const unsigned int r = (b + 0x7fffu + ((b >> 16) & 1u)) >> 16;  // RNE to bf16
    w1bt[l * 128 + i] = (unsigned short)r;
}

// ---------------------------------------------------------------------------
// node scores: s_node[n][i] = sum_l x[n][l]*MT[l][i] + b1[i]
// 32 nodes/block, thread tile = 4 nodes x 4 outputs
// ---------------------------------------------------------------------------
__global__ __launch_bounds__(256) void node_score_kernel(
    const float* __restrict__ x, const float* __restrict__ MT_g,
    const float* __restrict__ b1, float* __restrict__ s_node)
{
    __shared__ __align__(16) float mt_s[128 * 128];  // 64 KB
    const int t = threadIdx.x;
    for (int idx = t; idx < 4096; idx += 256)
        *(float4*)&mt_s[idx * 4] = *(const float4*)&MT_g[idx * 4];
    __syncthreads();

    const int n0   = blockIdx.x * 32;
    const int erow = t >> 5;          // 0..7 -> nodes erow*4 .. +3
    const int i4   = (t & 31) * 4;    // output quad

    float4 acc[4];
#pragma unroll
    for (int nn = 0; nn < 4; ++nn) acc[nn] = make_float4(0.f, 0.f, 0.f, 0.f);

    for (int l = 0; l < 128; l += 4) {
        float4 m0 = *(const float4*)&mt_s[(l + 0) * 128 + i4];
        float4 m1 = *(const float4*)&mt_s[(l + 1) * 128 + i4];
        float4 m2 = *(const float4*)&mt_s[(l + 2) * 128 + i4];
        float4 m3 = *(const float4*)&mt_s[(l + 3) * 128 + i4];
#pragma unroll
        for (int nn = 0; nn < 4; ++nn) {
            const float4 xv = *(const float4*)&x[(size_t)(n0 + erow * 4 + nn) * 128 + l];
            acc[nn] = fma4(xv.x, m0, acc[nn]);
            acc[nn] = fma4(xv.y, m1, acc[nn]);
            acc[nn] = fma4(xv.z, m2, acc[nn]);
            acc[nn] = fma4(xv.w, m3, acc[nn]);
        }
    }
    const float4 b1v = *(const float4*)&b1[i4];
#pragma unroll
    for (int nn = 0; nn < 4; ++nn) {
        float4 o = acc[nn];
        o.x += b1v.x; o.y += b1v.y; o.z += b1v.z; o.w += b1v.w;
        *(float4*)&s_node[(size_t)(n0 + erow * 4 + nn) * 128 + i4] = o;
    }
}

// ---------------------------------------------------------------------------
// edge scores: k = leaky(ea@Wk^T); t = k@W1b^T; pre = t + s_node[tgt];
// score = relu(pre).W2 + b2; ev = exp(score); denom[tgt] += ev
// 32 edges/tile, persistent blocks, thread tile = 4 edges x 4 outputs
// ---------------------------------------------------------------------------
__global__ __launch_bounds__(256) void edge_score_kernel(
    const float* __restrict__ edge_attr, const int* __restrict__ tgt,
    const float* __restrict__ Wk, const unsigned short* __restrict__ w1bt_g,
    const float* __restrict__ W2, const float* __restrict__ b2,
    const float* __restrict__ s_node,
    float* __restrict__ e_vals, float* __restrict__ denom)
{
    __shared__ __align__(16) unsigned short w1bt_s[128 * 128];  // 32 KB, [j][i]
    __shared__ __align__(16) float kT[128 * 32];                // 16 KB, [j][e]
    __shared__ __align__(16) float wk_s[128 * 12];              // 6 KB, padded rows
    __shared__ float ea_s[320];
    __shared__ int   tgt_s[32];

    const int t = threadIdx.x;
    // one-time stages (covered by first loop-top barrier)
    for (int idx = t; idx < 2048; idx += 256)
        *(uint4*)&w1bt_s[idx * 8] = *(const uint4*)&w1bt_g[idx * 8];
    for (int idx = t; idx < 1280; idx += 256)
        wk_s[(idx / 10) * 12 + (idx % 10)] = Wk[idx];

    const int icol = t & 31;
    const int erow = t >> 5;
    const int i4   = icol * 4;
    const float4 w2r = *(const float4*)&W2[i4];
    const float  b2v = b2[0];

    for (int tile = blockIdx.x; tile < NE / 32; tile += gridDim.x) {
        const int e0 = tile * 32;
        __syncthreads();  // protect ea_s/tgt_s/kT from previous iteration
        for (int idx = t; idx < 320; idx += 256)
            ea_s[idx] = edge_attr[(size_t)e0 * 10 + idx];
        if (t < 32) tgt_s[t] = tgt[e0 + t];
        __syncthreads();

        // phase 1: k for 32 edges; thread = (edge=icol, jblock=erow)
        {
            float ear[10];
#pragma unroll
            for (int c = 0; c < 10; ++c) ear[c] = ea_s[icol * 10 + c];
#pragma unroll
            for (int jj = 0; jj < 16; ++jj) {
                const int j = erow * 16 + jj;
                const float4 wa = *(const float4*)&wk_s[j * 12];
                const float4 wb = *(const float4*)&wk_s[j * 12 + 4];
                const float2 wc = *(const float2*)&wk_s[j * 12 + 8];
                float u = ear[0] * wa.x;
                u = fmaf(ear[1], wa.y, u);
                u = fmaf(ear[2], wa.z, u);
                u = fmaf(ear[3], wa.w, u);
                u = fmaf(ear[4], wb.x, u);
                u = fmaf(ear[5], wb.y, u);
                u = fmaf(ear[6], wb.z, u);
                u = fmaf(ear[7], wb.w, u);
                u = fmaf(ear[8], wc.x, u);
                u = fmaf(ear[9], wc.y, u);
                kT[j * 32 + icol] = (u >= 0.f) ? u : 0.01f * u;
            }
        }
        __syncthreads();

        // phase 2: t = k @ W1b^T, 4 edges x 4 outputs per thread
        float4 acc[4];
#pragma unroll
        for (int nn = 0; nn < 4; ++nn) acc[nn] = make_float4(0.f, 0.f, 0.f, 0.f);
#pragma unroll 2
        for (int j = 0; j < 128; ++j) {
            const float4 k4 = *(const float4*)&kT[j * 32 + erow * 4];
            const uint2 mu = *(const uint2*)&w1bt_s[j * 128 + i4];
            float4 m;
            m.x = __uint_as_float(mu.x << 16);
            m.y = __uint_as_float(mu.x & 0xffff0000u);
            m.z = __uint_as_float(mu.y << 16);
            m.w = __uint_as_float(mu.y & 0xffff0000u);
            acc[0] = fma4(k4.x, m, acc[0]);
            acc[1] = fma4(k4.y, m, acc[1]);
            acc[2] = fma4(k4.z, m, acc[2]);
            acc[3] = fma4(k4.w, m, acc[3]);
        }

        // epilogue: add s_node[tgt], relu, dot W2, reduce over 32 icol lanes
#pragma unroll
        for (int nn = 0; nn < 4; ++nn) {
            const int e  = erow * 4 + nn;
            const int tg = tgt_s[e];
            const float4 s4 = *(const float4*)&s_node[(size_t)tg * 128 + i4];
            float p = fmaxf(acc[nn].x + s4.x, 0.f) * w2r.x
                    + fmaxf(acc[nn].y + s4.y, 0.f) * w2r.y
                    + fmaxf(acc[nn].z + s4.z, 0.f) * w2r.z
                    + fmaxf(acc[nn].w + s4.w, 0.f) * w2r.w;
            p += __shfl_xor(p, 16);
            p += __shfl_xor(p, 8);
            p += __shfl_xor(p, 4);
            p += __shfl_xor(p, 2);
            p += __shfl_xor(p, 1);
            if (icol == 0) {
                const float ev = expf(p + b2v);  // no max-subtraction: |score| < ~1
                e_vals[e0 + e] = ev;
                atomicAdd(&denom[tg], ev);
            }
        }
    }
}

// ---------------------------------------------------------------------------
// scatter: attn = ev/(denom[tgt]+eps); v = leaky(ea@Wv^T + bv);
// out[tgt] += attn*v ; attn_out[e] = attn
// 2 edges per block-iteration, 128 threads each (one output dim per thread)
// ---------------------------------------------------------------------------
__global__ __launch_bounds__(256) void scatter_kernel(
    const float* __restrict__ edge_attr, const int* __restrict__ tgt,
    const float* __restrict__ Wv, const float* __restrict__ bv,
    const float* __restrict__ e_vals, const float* __restrict__ denom,
    float* __restrict__ out, float* __restrict__ attn_out)
{
    const int t    = threadIdx.x;
    const int half = t >> 7;
    const int i    = t & 127;
    float wv[10];
#pragma unroll
    for (int c = 0; c < 10; ++c) wv[c] = Wv[i * 10 + c];
    const float bvi = bv[i];

    for (int pair = blockIdx.x; pair < NE / 2; pair += gridDim.x) {
        const int e  = pair * 2 + half;
        const int tg = tgt[e];
        const float ev   = e_vals[e];
        const float attn = ev / (denom[tg] + 1e-16f);
        if (i == 0) attn_out[e] = attn;
        float u = bvi;
#pragma unroll
        for (int c = 0; c < 10; ++c)
            u = fmaf(edge_attr[(size_t)e * 10 + c], wv[c], u);
        const float v = (u >= 0.f) ? u : 0.01f * u;
        atomicAdd(&out[(size_t)tg * 128 + i], v * attn);
    }
}

extern "C" void kernel_launch(void* const* d_in, const int* in_sizes, int n_in,
                              void* d_out, int out_size, void* d_ws, size_t ws_size,
                              hipStream_t stream)
{
    const float* x         = (const float*)d_in[0];
    const int*   eidx      = (const int*)d_in[1];
    const float* edge_attr = (const float*)d_in[2];
    const float* Wq        = (const float*)d_in[3];
    const float* Wk        = (const float*)d_in[4];
    const float* Wv        = (const float*)d_in[5];
    const float* bv        = (const float*)d_in[6];
    const float* W1        = (const float*)d_in[7];
    const float* b1        = (const float*)d_in[8];
    const float* W2        = (const float*)d_in[9];
    const float* b2        = (const float*)d_in[10];
    const int*   tgt       = eidx + NE;  // edge_index[1]

    char* ws = (char*)d_ws;
    float*          denom  = (float*)(ws + OFF_DENOM);
    float*          MT     = (float*)(ws + OFF_MT);
    unsigned short* w1bt   = (unsigned short*)(ws + OFF_W1BT);
    float*          e_vals = (float*)(ws + OFF_EVALS);
    float*          s_node = (float*)(ws + OFF_SNODE);

    float* out      = (float*)d_out;
    float* attn_out = out + (size_t)NN * 128;

    hipMemsetAsync(d_out, 0, (size_t)NN * 128 * sizeof(float), stream);
    hipMemsetAsync(denom, 0, (size_t)NN * sizeof(float), stream);

    prep_kernel<<<128, 128, 0, stream>>>(W1, Wq, MT, w1bt);
    node_score_kernel<<<NN / 32, 256, 0, stream>>>(x, MT, b1, s_node);
    edge_score_kernel<<<2048, 256, 0, stream>>>(edge_attr, tgt, Wk, w1bt, W2, b2,
                                                s_node, e_vals, denom);
    scatter_kernel<<<4096, 256, 0, stream>>>(edge_attr, tgt, Wv, bv, e_vals, denom,
                                             out, attn_out);
}

// Round 3
// 703.802 us; speedup vs baseline: 1.7680x; 1.7680x over previous
//
#include <hip/hip_runtime.h>
#include <stdint.h>

#define NN 100000
#define NE 1000000
#define NTILES (NE / 64)

typedef __attribute__((ext_vector_type(8))) short bf16x8;
typedef __attribute__((ext_vector_type(4))) float f32x4;

// ws layout (bytes)
static const size_t OFF_DENOM = 0;                    // NN f32
static const size_t OFF_MT    = 1u << 19;             // 16384 f32: MT[l][i] = (W1a@Wq)[i][l]
static const size_t OFF_W1K   = OFF_MT + 65536;       // 128*32 bf16: Wk zero-padded K->32
static const size_t OFF_W1BP  = OFF_W1K + 8192;       // 128*128 bf16: W1b slot-permuted
static const size_t OFF_EVALS = OFF_W1BP + 32768;     // NE f32
static const size_t OFF_SNODE = OFF_EVALS + 4000000;  // NN*128 bf16 (25.6 MB)

__device__ inline unsigned short f2bf(float f) {
    const unsigned int u = __float_as_uint(f);
    return (unsigned short)((u + 0x7fffu + ((u >> 16) & 1u)) >> 16);  // RNE
}

__device__ inline float4 fma4(float a, float4 b, float4 c) {
    c.x = fmaf(a, b.x, c.x);
    c.y = fmaf(a, b.y, c.y);
    c.z = fmaf(a, b.z, c.z);
    c.w = fmaf(a, b.w, c.w);
    return c;
}

// ---------------------------------------------------------------------------
// prep: MT[l][i] = (W1a@Wq)[i][l]  (f32, for node_score)
//       w1k[j][c] = bf16(Wk[j][c]) zero-padded to K=32        (j=blk, c=thr<32)
//       w1bp[i][m] = bf16(W1[i][128 + j(m)]), slot-permuted   (m=blk, i=thr)
// j(m) matches phase-1 MFMA output register order so phase-2 B-frags come
// straight from phase-1 accumulators (k-slot bijection freedom).
// ---------------------------------------------------------------------------
__global__ __launch_bounds__(128) void prep_kernel(
    const float* __restrict__ W1, const float* __restrict__ Wq,
    const float* __restrict__ Wk,
    float* __restrict__ MT, unsigned short* __restrict__ w1k,
    unsigned short* __restrict__ w1bp)
{
    const int l = blockIdx.x;   // 0..127
    const int i = threadIdx.x;  // 0..127
    float acc = 0.f;
#pragma unroll 8
    for (int j = 0; j < 128; ++j)
        acc = fmaf(W1[i * 256 + j], Wq[j * 128 + l], acc);
    MT[l * 128 + i] = acc;
    if (i < 32)
        w1k[l * 32 + i] = (i < 10) ? f2bf(Wk[l * 10 + i]) : (unsigned short)0;
    const int m = l;
    const int j = (m & ~31) + 16 * ((m >> 2) & 1) + 4 * ((m >> 3) & 3) + (m & 3);
    w1bp[i * 128 + m] = f2bf(W1[i * 256 + 128 + j]);
}

// ---------------------------------------------------------------------------
// node scores: s_node[n][i] = bf16( sum_l x[n][l]*MT[l][i] + b1[i] )
// ---------------------------------------------------------------------------
__global__ __launch_bounds__(256) void node_score_kernel(
    const float* __restrict__ x, const float* __restrict__ MT_g,
    const float* __restrict__ b1, unsigned short* __restrict__ s_node)
{
    __shared__ __align__(16) float mt_s[128 * 128];  // 64 KB
    const int t = threadIdx.x;
    for (int idx = t; idx < 4096; idx += 256)
        *(float4*)&mt_s[idx * 4] = *(const float4*)&MT_g[idx * 4];
    __syncthreads();

    const int n0   = blockIdx.x * 32;
    const int erow = t >> 5;
    const int i4   = (t & 31) * 4;

    float4 acc[4];
#pragma unroll
    for (int nn = 0; nn < 4; ++nn) acc[nn] = make_float4(0.f, 0.f, 0.f, 0.f);

    for (int l = 0; l < 128; l += 4) {
        float4 m0 = *(const float4*)&mt_s[(l + 0) * 128 + i4];
        float4 m1 = *(const float4*)&mt_s[(l + 1) * 128 + i4];
        float4 m2 = *(const float4*)&mt_s[(l + 2) * 128 + i4];
        float4 m3 = *(const float4*)&mt_s[(l + 3) * 128 + i4];
#pragma unroll
        for (int nn = 0; nn < 4; ++nn) {
            const float4 xv = *(const float4*)&x[(size_t)(n0 + erow * 4 + nn) * 128 + l];
            acc[nn] = fma4(xv.x, m0, acc[nn]);
            acc[nn] = fma4(xv.y, m1, acc[nn]);
            acc[nn] = fma4(xv.z, m2, acc[nn]);
            acc[nn] = fma4(xv.w, m3, acc[nn]);
        }
    }
    const float4 b1v = *(const float4*)&b1[i4];
#pragma unroll
    for (int nn = 0; nn < 4; ++nn) {
        ushort4 o4;
        o4.x = f2bf(acc[nn].x + b1v.x);
        o4.y = f2bf(acc[nn].y + b1v.y);
        o4.z = f2bf(acc[nn].z + b1v.z);
        o4.w = f2bf(acc[nn].w + b1v.w);
        *(ushort4*)&s_node[(size_t)(n0 + erow * 4 + nn) * 128 + i4] = o4;
    }
}

// ---------------------------------------------------------------------------
// edge scores via MFMA. Each wave owns 16 edges end-to-end; no tile-loop
// barriers. Phase 1: k = leaky(ea@Wk^T) (8 MFMA, K=32 zero-padded).
// Phase 2: t = k@W1b^T (32 MFMA) with B-frags taken directly from phase-1
// accumulators (W1b pre-permuted to match). Epilogue: +s_node[tgt] (bf16
// gather, prefetched), relu, dot W2, cross-lane reduce, exp, atomic denom.
// ---------------------------------------------------------------------------
__global__ __launch_bounds__(256) void edge_kernel(
    const float* __restrict__ edge_attr, const int* __restrict__ tgt,
    const unsigned short* __restrict__ w1k_g, const unsigned short* __restrict__ w1bp_g,
    const float* __restrict__ W2, const float* __restrict__ b2,
    const unsigned short* __restrict__ s_node,
    float* __restrict__ e_vals, float* __restrict__ denom)
{
    __shared__ __align__(16) unsigned short w1b_s[128 * 136];  // padded rows: 272B stride

    const int t = threadIdx.x;
    // one-time stage of permuted W1b: 128*128 bf16 = 2048 uint4 (rows padded ->136)
    for (int idx = t; idx < 2048; idx += 256) {
        const uint4 v = ((const uint4*)w1bp_g)[idx];
        const int row = idx >> 4, q = idx & 15;
        *(uint4*)&w1b_s[row * 136 + q * 8] = v;
    }

    const int lane = t & 63;
    const int wave = t >> 6;
    const int h    = lane >> 4;   // k-slot group / row sub-block
    const int e15  = lane & 15;   // this lane's edge within the wave's 16

    // stationary A1 frags: Wk rows (one-time global read)
    bf16x8 a1[8];
#pragma unroll
    for (int f = 0; f < 8; ++f)
        a1[f] = *(const bf16x8*)&w1k_g[(f * 16 + e15) * 32 + h * 8];
    const float b2v = b2[0];

    __syncthreads();

    const int lds_base = e15 * 136 + h * 8;  // ushort units

    for (int tile = blockIdx.x; tile < NTILES; tile += gridDim.x) {
        const int ebase = tile * 64 + wave * 16;
        const int e     = ebase + e15;
        const int tg    = tgt[e];

        // prefetch s_node[tg] quads (bf16) to hide L2/L3 latency under MFMA
        uint2 sn[8];
#pragma unroll
        for (int g = 0; g < 8; ++g)
            sn[g] = *(const uint2*)&s_node[(size_t)tg * 128 + g * 16 + h * 4];

        // B1 frag: edge_attr channels c = h*8 + [0..7], zeros past c=9
        bf16x8 b1 = (bf16x8){0, 0, 0, 0, 0, 0, 0, 0};
        const float* pa = edge_attr + (size_t)e * 10;
        if (h == 0) {
            const float2 u0 = *(const float2*)(pa + 0);
            const float2 u1 = *(const float2*)(pa + 2);
            const float2 u2 = *(const float2*)(pa + 4);
            const float2 u3 = *(const float2*)(pa + 6);
            b1[0] = (short)f2bf(u0.x); b1[1] = (short)f2bf(u0.y);
            b1[2] = (short)f2bf(u1.x); b1[3] = (short)f2bf(u1.y);
            b1[4] = (short)f2bf(u2.x); b1[5] = (short)f2bf(u2.y);
            b1[6] = (short)f2bf(u3.x); b1[7] = (short)f2bf(u3.y);
        } else if (h == 1) {
            const float2 u4 = *(const float2*)(pa + 8);
            b1[0] = (short)f2bf(u4.x); b1[1] = (short)f2bf(u4.y);
        }

        // phase 1: k[j][e] for j = 16f + 4h + r
        const f32x4 z4 = {0.f, 0.f, 0.f, 0.f};
        f32x4 acc1[8];
#pragma unroll
        for (int f = 0; f < 8; ++f)
            acc1[f] = __builtin_amdgcn_mfma_f32_16x16x32_bf16(a1[f], b1, z4, 0, 0, 0);

        // leaky + pack: phase-2 B frags straight from acc1 (slot-matched)
        bf16x8 pbf[4];
#pragma unroll
        for (int s = 0; s < 4; ++s) {
            bf16x8 pb;
#pragma unroll
            for (int e8 = 0; e8 < 8; ++e8) {
                float v = acc1[2 * s + (e8 >> 2)][e8 & 3];
                v = (v >= 0.f) ? v : 0.01f * v;
                pb[e8] = (short)f2bf(v);
            }
            pbf[s] = pb;
        }

        // phase 2: t[i][e], i = 16g + 4h + r
        f32x4 acc2[8];
#pragma unroll
        for (int g = 0; g < 8; ++g) acc2[g] = z4;
#pragma unroll
        for (int s = 0; s < 4; ++s) {
#pragma unroll
            for (int g = 0; g < 8; ++g) {
                const bf16x8 a2 = *(const bf16x8*)&w1b_s[lds_base + g * (16 * 136) + s * 32];
                acc2[g] = __builtin_amdgcn_mfma_f32_16x16x32_bf16(a2, pbf[s], acc2[g], 0, 0, 0);
            }
        }

        // epilogue: p = sum_i relu(t + s_node) * W2
        float p = 0.f;
#pragma unroll
        for (int g = 0; g < 8; ++g) {
            const float4 w2v = *(const float4*)&W2[g * 16 + h * 4];
            const uint2 sv = sn[g];
            const float s0 = __uint_as_float(sv.x << 16);
            const float s1 = __uint_as_float(sv.x & 0xffff0000u);
            const float s2 = __uint_as_float(sv.y << 16);
            const float s3 = __uint_as_float(sv.y & 0xffff0000u);
            p = fmaf(fmaxf(acc2[g][0] + s0, 0.f), w2v.x, p);
            p = fmaf(fmaxf(acc2[g][1] + s1, 0.f), w2v.y, p);
            p = fmaf(fmaxf(acc2[g][2] + s2, 0.f), w2v.z, p);
            p = fmaf(fmaxf(acc2[g][3] + s3, 0.f), w2v.w, p);
        }
        p += __shfl_xor(p, 16);
        p += __shfl_xor(p, 32);
        if (lane < 16) {
            const float ev = expf(p + b2v);  // |score| small; no max-shift needed
            e_vals[ebase + lane] = ev;
            atomicAdd(&denom[tg], ev);
        }
    }
}

// ---------------------------------------------------------------------------
// scatter: attn = ev/(denom[tgt]+eps); v = leaky(ea@Wv^T + bv);
// out[tgt] += attn*v ; attn_out[e] = attn
// ---------------------------------------------------------------------------
__global__ __launch_bounds__(256) void scatter_kernel(
    const float* __restrict__ edge_attr, const int* __restrict__ tgt,
    const float* __restrict__ Wv, const float* __restrict__ bv,
    const float* __restrict__ e_vals, const float* __restrict__ denom,
    float* __restrict__ out, float* __restrict__ attn_out)
{
    const int t    = threadIdx.x;
    const int half = t >> 7;
    const int i    = t & 127;
    float wv[10];
#pragma unroll
    for (int c = 0; c < 10; ++c) wv[c] = Wv[i * 10 + c];
    const float bvi = bv[i];

    for (int pair = blockIdx.x; pair < NE / 2; pair += gridDim.x) {
        const int e  = pair * 2 + half;
        const int tg = tgt[e];
        const float ev   = e_vals[e];
        const float attn = ev / (denom[tg] + 1e-16f);
        if (i == 0) attn_out[e] = attn;
        float u = bvi;
#pragma unroll
        for (int c = 0; c < 10; ++c)
            u = fmaf(edge_attr[(size_t)e * 10 + c], wv[c], u);
        const float v = (u >= 0.f) ? u : 0.01f * u;
        atomicAdd(&out[(size_t)tg * 128 + i], v * attn);
    }
}

extern "C" void kernel_launch(void* const* d_in, const int* in_sizes, int n_in,
                              void* d_out, int out_size, void* d_ws, size_t ws_size,
                              hipStream_t stream)
{
    const float* x         = (const float*)d_in[0];
    const int*   eidx      = (const int*)d_in[1];
    const float* edge_attr = (const float*)d_in[2];
    const float* Wq        = (const float*)d_in[3];
    const float* Wk        = (const float*)d_in[4];
    const float* Wv        = (const float*)d_in[5];
    const float* bv        = (const float*)d_in[6];
    const float* W1        = (const float*)d_in[7];
    const float* b1        = (const float*)d_in[8];
    const float* W2        = (const float*)d_in[9];
    const float* b2        = (const float*)d_in[10];
    const int*   tgt       = eidx + NE;  // edge_index[1]

    char* ws = (char*)d_ws;
    float*          denom  = (float*)(ws + OFF_DENOM);
    float*          MT     = (float*)(ws + OFF_MT);
    unsigned short* w1k    = (unsigned short*)(ws + OFF_W1K);
    unsigned short* w1bp   = (unsigned short*)(ws + OFF_W1BP);
    float*          e_vals = (float*)(ws + OFF_EVALS);
    unsigned short* s_node = (unsigned short*)(ws + OFF_SNODE);

    float* out      = (float*)d_out;
    float* attn_out = out + (size_t)NN * 128;

    hipMemsetAsync(d_out, 0, (size_t)NN * 128 * sizeof(float), stream);
    hipMemsetAsync(denom, 0, (size_t)NN * sizeof(float), stream);

    prep_kernel<<<128, 128, 0, stream>>>(W1, Wq, Wk, MT, w1k, w1bp);
    node_score_kernel<<<NN / 32, 256, 0, stream>>>(x, MT, b1, s_node);
    edge_kernel<<<768, 256, 0, stream>>>(edge_attr, tgt, w1k, w1bp, W2, b2,
                                         s_node, e_vals, denom);
    scatter_kernel<<<4096, 256, 0, stream>>>(edge_attr, tgt, Wv, bv, e_vals, denom,
                                             out, attn_out);
}

// Round 4
// 492.253 us; speedup vs baseline: 2.5278x; 1.4298x over previous
//
#include <hip/hip_runtime.h>
#include <stdint.h>

#define NN 100000
#define NE 1000000
#define NTILES (NE / 64)
#define NB_SCAN 391  // ceil(NN/256)

typedef __attribute__((ext_vector_type(8))) short bf16x8;
typedef __attribute__((ext_vector_type(4))) float f32x4;

// ws layout (bytes)
static const size_t OFF_MT    = 0;                    // 16384 f32
static const size_t OFF_W1K   = 65536;                // 128*32 bf16
static const size_t OFF_W1BP  = 73728;                // 128*128 bf16
static const size_t OFF_RP    = 131072;               // (NN+1) int rowptr
static const size_t OFF_CUR   = 1u << 20;             // NN int cursor
static const size_t OFF_PART  = 1572864;              // NB_SCAN*256 int partial scans
static const size_t OFF_BSUM  = 2097152;              // NB_SCAN int block sums
static const size_t OFF_BSUMX = 2101248;              // NB_SCAN int block-sum exclusive scan
static const size_t OFF_CNT   = 2105344;              // NN int histogram
static const size_t OFF_PERM  = 1u << 22;             // NE int edge permutation
static const size_t OFF_EVALS = 8388608;              // NE f32
static const size_t OFF_SNODE = 1u << 24;             // NN*128 bf16 (25.6 MB)
// total ≈ 42.4 MB

__device__ inline unsigned short f2bf(float f) {
    const unsigned int u = __float_as_uint(f);
    return (unsigned short)((u + 0x7fffu + ((u >> 16) & 1u)) >> 16);  // RNE
}

__device__ inline float4 fma4(float a, float4 b, float4 c) {
    c.x = fmaf(a, b.x, c.x);
    c.y = fmaf(a, b.y, c.y);
    c.z = fmaf(a, b.z, c.z);
    c.w = fmaf(a, b.w, c.w);
    return c;
}

// ---------------------------------------------------------------------------
// prep: MT[l][i] = (W1a@Wq)[i][l]; w1k = bf16(Wk) K-padded; w1bp = W1b slot-
// permuted bf16 (phase-1 MFMA output order == phase-2 B-fragment order).
// ---------------------------------------------------------------------------
__global__ __launch_bounds__(128) void prep_kernel(
    const float* __restrict__ W1, const float* __restrict__ Wq,
    const float* __restrict__ Wk,
    float* __restrict__ MT, unsigned short* __restrict__ w1k,
    unsigned short* __restrict__ w1bp)
{
    const int l = blockIdx.x;
    const int i = threadIdx.x;
    float acc = 0.f;
#pragma unroll 8
    for (int j = 0; j < 128; ++j)
        acc = fmaf(W1[i * 256 + j], Wq[j * 128 + l], acc);
    MT[l * 128 + i] = acc;
    if (i < 32)
        w1k[l * 32 + i] = (i < 10) ? f2bf(Wk[l * 10 + i]) : (unsigned short)0;
    const int m = l;
    const int j = (m & ~31) + 16 * ((m >> 2) & 1) + 4 * ((m >> 3) & 3) + (m & 3);
    w1bp[i * 128 + m] = f2bf(W1[i * 256 + 128 + j]);
}

// ---------------------------------------------------------------------------
// node scores: s_node[n][i] = bf16( x[n] @ MT + b1 )
// ---------------------------------------------------------------------------
__global__ __launch_bounds__(256) void node_score_kernel(
    const float* __restrict__ x, const float* __restrict__ MT_g,
    const float* __restrict__ b1, unsigned short* __restrict__ s_node)
{
    __shared__ __align__(16) float mt_s[128 * 128];
    const int t = threadIdx.x;
    for (int idx = t; idx < 4096; idx += 256)
        *(float4*)&mt_s[idx * 4] = *(const float4*)&MT_g[idx * 4];
    __syncthreads();

    const int n0   = blockIdx.x * 32;
    const int erow = t >> 5;
    const int i4   = (t & 31) * 4;

    float4 acc[4];
#pragma unroll
    for (int nn = 0; nn < 4; ++nn) acc[nn] = make_float4(0.f, 0.f, 0.f, 0.f);

    for (int l = 0; l < 128; l += 4) {
        float4 m0 = *(const float4*)&mt_s[(l + 0) * 128 + i4];
        float4 m1 = *(const float4*)&mt_s[(l + 1) * 128 + i4];
        float4 m2 = *(const float4*)&mt_s[(l + 2) * 128 + i4];
        float4 m3 = *(const float4*)&mt_s[(l + 3) * 128 + i4];
#pragma unroll
        for (int nn = 0; nn < 4; ++nn) {
            const float4 xv = *(const float4*)&x[(size_t)(n0 + erow * 4 + nn) * 128 + l];
            acc[nn] = fma4(xv.x, m0, acc[nn]);
            acc[nn] = fma4(xv.y, m1, acc[nn]);
            acc[nn] = fma4(xv.z, m2, acc[nn]);
            acc[nn] = fma4(xv.w, m3, acc[nn]);
        }
    }
    const float4 b1v = *(const float4*)&b1[i4];
#pragma unroll
    for (int nn = 0; nn < 4; ++nn) {
        ushort4 o4;
        o4.x = f2bf(acc[nn].x + b1v.x);
        o4.y = f2bf(acc[nn].y + b1v.y);
        o4.z = f2bf(acc[nn].z + b1v.z);
        o4.w = f2bf(acc[nn].w + b1v.w);
        *(ushort4*)&s_node[(size_t)(n0 + erow * 4 + nn) * 128 + i4] = o4;
    }
}

// ---------------------------------------------------------------------------
// CSR build: histogram -> block scan (3 kernels) -> fill perm
// ---------------------------------------------------------------------------
__global__ __launch_bounds__(256) void hist_kernel(
    const int* __restrict__ tgt, int* __restrict__ cnt)
{
    const int e = blockIdx.x * 256 + threadIdx.x;
    if (e < NE) atomicAdd(&cnt[tgt[e]], 1);
}

__global__ __launch_bounds__(256) void scan1_kernel(
    const int* __restrict__ cnt, int* __restrict__ part, int* __restrict__ bsum)
{
    __shared__ int s[256];
    const int t = threadIdx.x;
    const int idx = blockIdx.x * 256 + t;
    const int v = (idx < NN) ? cnt[idx] : 0;
    s[t] = v;
    __syncthreads();
    for (int off = 1; off < 256; off <<= 1) {
        const int u = (t >= off) ? s[t - off] : 0;
        __syncthreads();
        s[t] += u;
        __syncthreads();
    }
    part[idx] = s[t] - v;  // exclusive
    if (t == 255) bsum[blockIdx.x] = s[255];
}

__global__ __launch_bounds__(512) void scan2_kernel(
    const int* __restrict__ bsum, int* __restrict__ bsumx)
{
    __shared__ int s[512];
    const int t = threadIdx.x;
    const int v = (t < NB_SCAN) ? bsum[t] : 0;
    s[t] = v;
    __syncthreads();
    for (int off = 1; off < 512; off <<= 1) {
        const int u = (t >= off) ? s[t - off] : 0;
        __syncthreads();
        s[t] += u;
        __syncthreads();
    }
    if (t < NB_SCAN) bsumx[t] = s[t] - v;  // exclusive
}

__global__ __launch_bounds__(256) void scan3_kernel(
    const int* __restrict__ part, const int* __restrict__ bsumx,
    int* __restrict__ rowptr, int* __restrict__ cursor)
{
    const int idx = blockIdx.x * 256 + threadIdx.x;
    if (idx < NN) {
        const int rp = part[idx] + bsumx[idx >> 8];
        rowptr[idx] = rp;
        cursor[idx] = rp;
    }
    if (idx == 0) rowptr[NN] = NE;
}

__global__ __launch_bounds__(256) void fill_kernel(
    const int* __restrict__ tgt, int* __restrict__ cursor, int* __restrict__ perm)
{
    const int e = blockIdx.x * 256 + threadIdx.x;
    if (e < NE) {
        const int p = atomicAdd(&cursor[tgt[e]], 1);
        perm[p] = e;
    }
}

// ---------------------------------------------------------------------------
// edge scores via MFMA (unchanged math; denom atomic removed).
// ---------------------------------------------------------------------------
__global__ __launch_bounds__(256) void edge_kernel(
    const float* __restrict__ edge_attr, const int* __restrict__ tgt,
    const unsigned short* __restrict__ w1k_g, const unsigned short* __restrict__ w1bp_g,
    const float* __restrict__ W2, const float* __restrict__ b2,
    const unsigned short* __restrict__ s_node,
    float* __restrict__ e_vals)
{
    __shared__ __align__(16) unsigned short w1b_s[128 * 136];

    const int t = threadIdx.x;
    for (int idx = t; idx < 2048; idx += 256) {
        const uint4 v = ((const uint4*)w1bp_g)[idx];
        const int row = idx >> 4, q = idx & 15;
        *(uint4*)&w1b_s[row * 136 + q * 8] = v;
    }

    const int lane = t & 63;
    const int wave = t >> 6;
    const int h    = lane >> 4;
    const int e15  = lane & 15;

    bf16x8 a1[8];
#pragma unroll
    for (int f = 0; f < 8; ++f)
        a1[f] = *(const bf16x8*)&w1k_g[(f * 16 + e15) * 32 + h * 8];
    const float b2v = b2[0];

    __syncthreads();

    const int lds_base = e15 * 136 + h * 8;

    for (int tile = blockIdx.x; tile < NTILES; tile += gridDim.x) {
        const int ebase = tile * 64 + wave * 16;
        const int e     = ebase + e15;
        const int tg    = tgt[e];

        uint2 sn[8];
#pragma unroll
        for (int g = 0; g < 8; ++g)
            sn[g] = *(const uint2*)&s_node[(size_t)tg * 128 + g * 16 + h * 4];

        bf16x8 b1 = (bf16x8){0, 0, 0, 0, 0, 0, 0, 0};
        const float* pa = edge_attr + (size_t)e * 10;
        if (h == 0) {
            const float2 u0 = *(const float2*)(pa + 0);
            const float2 u1 = *(const float2*)(pa + 2);
            const float2 u2 = *(const float2*)(pa + 4);
            const float2 u3 = *(const float2*)(pa + 6);
            b1[0] = (short)f2bf(u0.x); b1[1] = (short)f2bf(u0.y);
            b1[2] = (short)f2bf(u1.x); b1[3] = (short)f2bf(u1.y);
            b1[4] = (short)f2bf(u2.x); b1[5] = (short)f2bf(u2.y);
            b1[6] = (short)f2bf(u3.x); b1[7] = (short)f2bf(u3.y);
        } else if (h == 1) {
            const float2 u4 = *(const float2*)(pa + 8);
            b1[0] = (short)f2bf(u4.x); b1[1] = (short)f2bf(u4.y);
        }

        const f32x4 z4 = {0.f, 0.f, 0.f, 0.f};
        f32x4 acc1[8];
#pragma unroll
        for (int f = 0; f < 8; ++f)
            acc1[f] = __builtin_amdgcn_mfma_f32_16x16x32_bf16(a1[f], b1, z4, 0, 0, 0);

        bf16x8 pbf[4];
#pragma unroll
        for (int s = 0; s < 4; ++s) {
            bf16x8 pb;
#pragma unroll
            for (int e8 = 0; e8 < 8; ++e8) {
                float v = acc1[2 * s + (e8 >> 2)][e8 & 3];
                v = (v >= 0.f) ? v : 0.01f * v;
                pb[e8] = (short)f2bf(v);
            }
            pbf[s] = pb;
        }

        f32x4 acc2[8];
#pragma unroll
        for (int g = 0; g < 8; ++g) acc2[g] = z4;
#pragma unroll
        for (int s = 0; s < 4; ++s) {
#pragma unroll
            for (int g = 0; g < 8; ++g) {
                const bf16x8 a2 = *(const bf16x8*)&w1b_s[lds_base + g * (16 * 136) + s * 32];
                acc2[g] = __builtin_amdgcn_mfma_f32_16x16x32_bf16(a2, pbf[s], acc2[g], 0, 0, 0);
            }
        }

        float p = 0.f;
#pragma unroll
        for (int g = 0; g < 8; ++g) {
            const float4 w2v = *(const float4*)&W2[g * 16 + h * 4];
            const uint2 sv = sn[g];
            const float s0 = __uint_as_float(sv.x << 16);
            const float s1 = __uint_as_float(sv.x & 0xffff0000u);
            const float s2 = __uint_as_float(sv.y << 16);
            const float s3 = __uint_as_float(sv.y & 0xffff0000u);
            p = fmaf(fmaxf(acc2[g][0] + s0, 0.f), w2v.x, p);
            p = fmaf(fmaxf(acc2[g][1] + s1, 0.f), w2v.y, p);
            p = fmaf(fmaxf(acc2[g][2] + s2, 0.f), w2v.z, p);
            p = fmaf(fmaxf(acc2[g][3] + s3, 0.f), w2v.w, p);
        }
        p += __shfl_xor(p, 16);
        p += __shfl_xor(p, 32);
        if (lane < 16)
            e_vals[ebase + lane] = expf(p + b2v);  // |score| small; no max-shift
    }
}

// ---------------------------------------------------------------------------
// gather: one wave per node, lane owns dims (2*lane, 2*lane+1).
// Phase A: parallel load of perm/e_vals, butterfly denom reduce, attn write.
// Phase B: serial edge loop — shfl-broadcast edge id/attn, wave-uniform
// edge_attr row load, 20 FMA/lane, register accumulate. One store per node.
// No atomics, no LDS, no barriers.
// ---------------------------------------------------------------------------
__global__ __launch_bounds__(256) void gather_kernel(
    const int* __restrict__ rowptr, const int* __restrict__ perm,
    const float* __restrict__ e_vals, const float* __restrict__ edge_attr,
    const float* __restrict__ Wv, const float* __restrict__ bv,
    float* __restrict__ out, float* __restrict__ attn_out)
{
    const int t    = threadIdx.x;
    const int lane = t & 63;
    const int wave = t >> 6;
    const int node = blockIdx.x * 4 + wave;
    const int d0   = lane * 2;

    float wv0[10], wv1[10];
#pragma unroll
    for (int c = 0; c < 10; ++c) {
        wv0[c] = Wv[d0 * 10 + c];
        wv1[c] = Wv[d0 * 10 + 10 + c];
    }
    const float bv0 = bv[d0], bv1 = bv[d0 + 1];

    const int start = rowptr[node];
    const int end   = rowptr[node + 1];

    // phase A: denominator
    float part = 0.f;
    for (int c = start + lane; c < end; c += 64) part += e_vals[perm[c]];
    part += __shfl_xor(part, 1);
    part += __shfl_xor(part, 2);
    part += __shfl_xor(part, 4);
    part += __shfl_xor(part, 8);
    part += __shfl_xor(part, 16);
    part += __shfl_xor(part, 32);
    const float inv = 1.f / (part + 1e-16f);

    float acc0 = 0.f, acc1 = 0.f;
    for (int c0 = start; c0 < end; c0 += 64) {
        const int m = min(64, end - c0);
        int ee = 0; float evl = 0.f;
        if (lane < m) {
            ee  = perm[c0 + lane];
            evl = e_vals[ee];
            attn_out[ee] = evl * inv;
        }
#pragma unroll 2
        for (int d = 0; d < m; ++d) {
            const int   eed = __shfl(ee, d);
            const float ad  = __shfl(evl, d) * inv;
            const float* pa = edge_attr + (size_t)eed * 10;
            const float2 u0 = *(const float2*)(pa + 0);
            const float2 u1 = *(const float2*)(pa + 2);
            const float2 u2 = *(const float2*)(pa + 4);
            const float2 u3 = *(const float2*)(pa + 6);
            const float2 u4 = *(const float2*)(pa + 8);
            float a0 = bv0, a1 = bv1;
            a0 = fmaf(u0.x, wv0[0], a0); a1 = fmaf(u0.x, wv1[0], a1);
            a0 = fmaf(u0.y, wv0[1], a0); a1 = fmaf(u0.y, wv1[1], a1);
            a0 = fmaf(u1.x, wv0[2], a0); a1 = fmaf(u1.x, wv1[2], a1);
            a0 = fmaf(u1.y, wv0[3], a0); a1 = fmaf(u1.y, wv1[3], a1);
            a0 = fmaf(u2.x, wv0[4], a0); a1 = fmaf(u2.x, wv1[4], a1);
            a0 = fmaf(u2.y, wv0[5], a0); a1 = fmaf(u2.y, wv1[5], a1);
            a0 = fmaf(u3.x, wv0[6], a0); a1 = fmaf(u3.x, wv1[6], a1);
            a0 = fmaf(u3.y, wv0[7], a0); a1 = fmaf(u3.y, wv1[7], a1);
            a0 = fmaf(u4.x, wv0[8], a0); a1 = fmaf(u4.x, wv1[8], a1);
            a0 = fmaf(u4.y, wv0[9], a0); a1 = fmaf(u4.y, wv1[9], a1);
            const float v0 = (a0 >= 0.f) ? a0 : 0.01f * a0;
            const float v1 = (a1 >= 0.f) ? a1 : 0.01f * a1;
            acc0 = fmaf(ad, v0, acc0);
            acc1 = fmaf(ad, v1, acc1);
        }
    }
    *(float2*)&out[(size_t)node * 128 + d0] = make_float2(acc0, acc1);
}

extern "C" void kernel_launch(void* const* d_in, const int* in_sizes, int n_in,
                              void* d_out, int out_size, void* d_ws, size_t ws_size,
                              hipStream_t stream)
{
    const float* x         = (const float*)d_in[0];
    const int*   eidx      = (const int*)d_in[1];
    const float* edge_attr = (const float*)d_in[2];
    const float* Wq        = (const float*)d_in[3];
    const float* Wk        = (const float*)d_in[4];
    const float* Wv        = (const float*)d_in[5];
    const float* bv        = (const float*)d_in[6];
    const float* W1        = (const float*)d_in[7];
    const float* b1        = (const float*)d_in[8];
    const float* W2        = (const float*)d_in[9];
    const float* b2        = (const float*)d_in[10];
    const int*   tgt       = eidx + NE;  // edge_index[1]

    char* ws = (char*)d_ws;
    float*          MT     = (float*)(ws + OFF_MT);
    unsigned short* w1k    = (unsigned short*)(ws + OFF_W1K);
    unsigned short* w1bp   = (unsigned short*)(ws + OFF_W1BP);
    int*            rowptr = (int*)(ws + OFF_RP);
    int*            cursor = (int*)(ws + OFF_CUR);
    int*            part   = (int*)(ws + OFF_PART);
    int*            bsum   = (int*)(ws + OFF_BSUM);
    int*            bsumx  = (int*)(ws + OFF_BSUMX);
    int*            cnt    = (int*)(ws + OFF_CNT);
    int*            perm   = (int*)(ws + OFF_PERM);
    float*          e_vals = (float*)(ws + OFF_EVALS);
    unsigned short* s_node = (unsigned short*)(ws + OFF_SNODE);

    float* out      = (float*)d_out;
    float* attn_out = out + (size_t)NN * 128;

    hipMemsetAsync(cnt, 0, (size_t)NN * sizeof(int), stream);

    prep_kernel<<<128, 128, 0, stream>>>(W1, Wq, Wk, MT, w1k, w1bp);
    node_score_kernel<<<NN / 32, 256, 0, stream>>>(x, MT, b1, s_node);
    hist_kernel<<<(NE + 255) / 256, 256, 0, stream>>>(tgt, cnt);
    scan1_kernel<<<NB_SCAN, 256, 0, stream>>>(cnt, part, bsum);
    scan2_kernel<<<1, 512, 0, stream>>>(bsum, bsumx);
    scan3_kernel<<<NB_SCAN, 256, 0, stream>>>(part, bsumx, rowptr, cursor);
    fill_kernel<<<(NE + 255) / 256, 256, 0, stream>>>(tgt, cursor, perm);
    edge_kernel<<<768, 256, 0, stream>>>(edge_attr, tgt, w1k, w1bp, W2, b2,
                                         s_node, e_vals);
    gather_kernel<<<NN / 4, 256, 0, stream>>>(rowptr, perm, e_vals, edge_attr,
                                              Wv, bv, out, attn_out);
}